// Round 1
// 248.898 us; speedup vs baseline: 1.1486x; 1.1486x over previous
//
#include <hip/hip_runtime.h>
#include <math.h>

// Qwen3Attention: T=2048, HID=2048, H=16, KV=8, D=128
#define T_TOK 2048
#define HID 2048
#define NH 16
#define NKV 8
#define HD 128
#define QKV_N 4096
#define EPS 1e-6f

typedef unsigned short u16;
typedef unsigned int   u32;
typedef __attribute__((ext_vector_type(8))) u16   u16x8;
typedef __attribute__((ext_vector_type(8))) short short8;
typedef __attribute__((ext_vector_type(4))) float floatx4;
typedef __attribute__((ext_vector_type(4))) u32   u32x4;

__device__ __forceinline__ u16 f2bf(float x) {           // RNE f32->bf16
    u32 u = __float_as_uint(x);
    u = (u + 0x7fffu + ((u >> 16) & 1u)) >> 16;
    return (u16)u;
}
__device__ __forceinline__ float bf2f(u16 h) {
    return __uint_as_float(((u32)h) << 16);
}

// ---------------------------------------------------------------------------
// f32 -> bf16 elementwise (8 elems/thread). n must be a multiple of 2048.
// ---------------------------------------------------------------------------
__global__ __launch_bounds__(256) void cvt_f32_bf16(
    const float* __restrict__ in, u16* __restrict__ out)
{
    const size_t i = ((size_t)blockIdx.x * 256 + threadIdx.x) * 8;
    float4 a = *(const float4*)(in + i);
    float4 b = *(const float4*)(in + i + 4);
    u16x8 o;
    o[0] = f2bf(a.x); o[1] = f2bf(a.y); o[2] = f2bf(a.z); o[3] = f2bf(a.w);
    o[4] = f2bf(b.x); o[5] = f2bf(b.y); o[6] = f2bf(b.z); o[7] = f2bf(b.w);
    *(u16x8*)(out + i) = o;
}

// ---------------------------------------------------------------------------
// bf16 MFMA GEMM, T2+T3+T4+T5 stack: C[M,N] = A[M,K]*B[N,K]^T
//   BM=256, BN=128, BK=64, 512 thr = 8 waves (4 row-groups x 2 col-groups),
//   wave tile 64x64, triple-buffered LDS ring (144 KB), prefetch distance 2,
//   counted s_waitcnt vmcnt(6) (never 0 in steady state), ONE barrier/K-tile,
//   XOR-swizzled LDS (chunk ^= row&7) staged via inverse-swizzled global src,
//   s_setprio(1) around each 8-MFMA cluster, sched_barrier phase fences.
// Invariant entering tile t: buf[t%3] landed+barriered, buf[(t+1)%3] issued.
// ---------------------------------------------------------------------------
#define GBM 256
#define GBN 128
#define GBK 64
#define BUFSH 24576   /* shorts per buffer: A 256*64 + B 128*64 */

#define WAITV6 asm volatile("s_waitcnt vmcnt(6)" ::: "memory")
#define WAITV0 asm volatile("s_waitcnt vmcnt(0)" ::: "memory")
#define LGKM0  asm volatile("s_waitcnt lgkmcnt(0)" ::: "memory")
#define BARR   asm volatile("s_barrier" ::: "memory")
#define SB     __builtin_amdgcn_sched_barrier(0)

#define STAGEU(i, tt, dstb) \
    __builtin_amdgcn_global_load_lds( \
        (const __attribute__((address_space(1))) u32*)(gsrc[i] + (size_t)(tt)*GBK), \
        (__attribute__((address_space(3))) u32*)((dstb) + loff[i]), 16, 0, 0)

#define RD_A(dst, srcb, f) do { \
    dst[0] = *(const short8*)((srcb) + arow + (f)*1024 + achunk0); \
    dst[1] = *(const short8*)((srcb) + arow + (f)*1024 + achunk1); } while (0)

#define RD_B(dst, srcb) do { \
    _Pragma("unroll") \
    for (int j_ = 0; j_ < 4; ++j_) { \
        dst[j_][0] = *(const short8*)((srcb) + 16384 + brow + j_*1024 + achunk0); \
        dst[j_][1] = *(const short8*)((srcb) + 16384 + brow + j_*1024 + achunk1); } } while (0)

#define MM(f, aa, bb) do { \
    __builtin_amdgcn_s_setprio(1); \
    _Pragma("unroll") \
    for (int j_ = 0; j_ < 4; ++j_) { \
        acc[f][j_] = __builtin_amdgcn_mfma_f32_16x16x32_bf16(aa[0], bb[j_][0], acc[f][j_], 0, 0, 0); \
        acc[f][j_] = __builtin_amdgcn_mfma_f32_16x16x32_bf16(aa[1], bb[j_][1], acc[f][j_], 0, 0, 0); } \
    __builtin_amdgcn_s_setprio(0); } while (0)

// One K-tile: 4 phases, 8 MFMA each; A-frags read one phase ahead (ping-pong),
// B-frags for tile t+1 read right after the per-tile barrier.
#define TILE(t, CURB, NXTB, THDB, BBC, BBN) do { \
    const bool st_ = (t) + 2 < nt; \
    if (st_) { STAGEU(0, (t)+2, THDB); STAGEU(1, (t)+2, THDB); } \
    RD_A(aP1, CURB, 1); SB; \
    MM(0, aP0, BBC); SB; \
    if (st_) { STAGEU(2, (t)+2, THDB); STAGEU(3, (t)+2, THDB); } \
    RD_A(aP0, CURB, 2); SB; \
    MM(1, aP1, BBC); SB; \
    if (st_) { STAGEU(4, (t)+2, THDB); STAGEU(5, (t)+2, THDB); } \
    RD_A(aP1, CURB, 3); SB; \
    MM(2, aP0, BBC); \
    if ((t) + 1 < nt) { \
        if (st_) { WAITV6; } else { WAITV0; } \
        LGKM0; BARR; SB; \
        RD_B(BBN, NXTB); RD_A(aP0, NXTB, 0); \
    } \
    SB; \
    MM(3, aP1, BBC); SB; \
} while (0)

template<bool OUT_BF16>
__global__ __launch_bounds__(512, 2) void gemm_bt_8p(
    const u16* __restrict__ A, const u16* __restrict__ B,
    void* __restrict__ Cv, int K, int lda, int ldb, int ldc)
{
    extern __shared__ short lds[];          // 3 * 24576 shorts = 144 KB
    const int tid = threadIdx.x;
    const int w  = tid >> 6;
    const int l  = tid & 63;
    const int m0 = blockIdx.y * GBM;
    const int n0 = blockIdx.x * GBN;
    const int mr = (w >> 1) * 64;           // wave row base within tile
    const int nc = (w & 1) * 64;            // wave col base within tile
    const int cc = l & 15;
    const int q4 = l >> 4;

    // ---- staging setup: 48 units (32 A + 16 B) of 8 rows x 64 cols; 6/wave.
    // LDS dest is linear (base + lane*16); global source is inverse-swizzled
    // so that phys chunk p of row r holds logical chunk p ^ (r&7).
    const int lr = l >> 3;                  // row within unit
    const int gchunk = ((l & 7) ^ (lr & 7)) * 8;   // logical chunk, u16 units
    const u16* gsrc[6]; int loff[6];
    #pragma unroll
    for (int i = 0; i < 6; ++i) {
        const int u = w * 6 + i;
        if (u < 32) {          // A rows m0 + u*8 ..
            gsrc[i] = A + (size_t)(m0 + u*8 + lr) * lda + gchunk;
            loff[i] = u * 512;
        } else {               // B rows n0 + (u-32)*8 ..
            const int v = u - 32;
            gsrc[i] = B + (size_t)(n0 + v*8 + lr) * ldb + gchunk;
            loff[i] = 16384 + v * 512;
        }
    }

    // ---- fragment read addressing (swizzled): row&7 == cc&7 always ----
    const int achunk0 = ((q4)     ^ (cc & 7)) * 8;   // k-step 0
    const int achunk1 = ((4 + q4) ^ (cc & 7)) * 8;   // k-step 1
    const int arow = (mr + cc) * 64;                 // + f*1024 shorts
    const int brow = (nc + cc) * 64;                 // + j*1024 shorts

    floatx4 acc[4][4];
    #pragma unroll
    for (int f = 0; f < 4; ++f)
        #pragma unroll
        for (int j = 0; j < 4; ++j) acc[f][j] = (floatx4){0.f, 0.f, 0.f, 0.f};

    short8 aP0[2], aP1[2], bbE[4][2], bbO[4][2];
    short* b0 = lds;
    short* b1 = lds + BUFSH;
    short* b2 = lds + 2 * BUFSH;
    const int nt = K >> 6;                  // K-tiles (even for our shapes)

    // ---- prologue: issue tiles 0,1; wait own tile-0 loads; barrier ----
    #pragma unroll
    for (int i = 0; i < 6; ++i) STAGEU(i, 0, b0);
    #pragma unroll
    for (int i = 0; i < 6; ++i) STAGEU(i, 1, b1);
    WAITV6; BARR; SB;
    RD_B(bbE, b0); RD_A(aP0, b0, 0);

    short *CURB = b0, *NXTB = b1, *THDB = b2;
    for (int t = 0; t < nt; t += 2) {
        TILE(t, CURB, NXTB, THDB, bbE, bbO);
        { short* tmp = CURB; CURB = NXTB; NXTB = THDB; THDB = tmp; }
        TILE(t + 1, CURB, NXTB, THDB, bbO, bbE);
        { short* tmp = CURB; CURB = NXTB; NXTB = THDB; THDB = tmp; }
    }

    // ---- epilogue: C/D layout col=lane&15, row=(lane>>4)*4+reg ----
    const int r0 = q4 * 4;
    #pragma unroll
    for (int f = 0; f < 4; ++f)
        #pragma unroll
        for (int j = 0; j < 4; ++j)
            #pragma unroll
            for (int r = 0; r < 4; ++r) {
                const int row = m0 + mr + f*16 + r0 + r;
                const int col = n0 + nc + j*16 + cc;
                if (OUT_BF16)
                    ((u16*)Cv)[(size_t)row * ldc + col] = f2bf(acc[f][j][r]);
                else
                    ((float*)Cv)[(size_t)row * ldc + col] = acc[f][j][r];
            }
}

// ---------------------------------------------------------------------------
// Fused prep: RMSNorm+RoPE for q heads {2kvh, 2kvh+1} and k head kvh
// (wave-per-row, shfl-based), K written directly into the packed swizzled
// DMA image, plus V transpose+pack. grid=(T/64, NKV), 256 thr = 4 waves.
// ---------------------------------------------------------------------------
__global__ __launch_bounds__(256) void prep(
    u16* __restrict__ qkv, const int* __restrict__ positions,
    const float* __restrict__ qw, const float* __restrict__ kw,
    u16* __restrict__ Kp, u16* __restrict__ Vtp)
{
    const int tile = blockIdx.x, kvh = blockIdx.y;
    const int tid = threadIdx.x;
    const int w = tid >> 6, l = tid & 63;
    const int t0 = tile * 64;

    const float qw0 = qw[2*l], qw1 = qw[2*l+1];
    const float kw0 = kw[2*l], kw1 = kw[2*l+1];
    const int   i0  = (2*l) & 63;            // rotary index (even)
    const float if0 = exp2f(-(float)i0     * 0.311430758895690f); // log2(1e6)/64
    const float if1 = exp2f(-(float)(i0+1) * 0.311430758895690f);

    for (int rr = w; rr < 64; rr += 4) {
        const int t = t0 + rr;
        const int pos = positions[t];
        const float a0 = (float)pos * if0;
        const float a1 = (float)pos * if1;
        const float s0 = sinf(a0), c0 = cosf(a0);   // NOTE: not sincosf (r2 trap)
        const float s1 = sinf(a1), c1 = cosf(a1);

        #pragma unroll
        for (int pass = 0; pass < 3; ++pass) {
            const int off = (pass < 2) ? (2*kvh + pass)*HD : NH*HD + kvh*HD;
            const float w0 = (pass < 2) ? qw0 : kw0;
            const float w1 = (pass < 2) ? qw1 : kw1;
            u16* p = qkv + (size_t)t*QKV_N + off;

            const u32 pk = *(const u32*)(p + 2*l);
            const float x0 = bf2f((u16)pk), x1 = bf2f((u16)(pk >> 16));
            float ss = x0*x0 + x1*x1;
            #pragma unroll
            for (int x = 1; x < 64; x <<= 1) ss += __shfl_xor(ss, x);
            const float rs = rsqrtf(ss * (1.0f/128.0f) + EPS);
            const float xn0 = x0 * rs * w0, xn1 = x1 * rs * w1;
            const float px0 = __shfl_xor(xn0, 32);
            const float px1 = __shfl_xor(xn1, 32);

            float o0, o1;
            if (l < 32) { o0 = xn0*c0 - px0*s0; o1 = xn1*c1 - px1*s1; }
            else        { o0 = xn0*c0 + px0*s0; o1 = xn1*c1 + px1*s1; }
            const u32 outpk = (u32)f2bf(o0) | ((u32)f2bf(o1) << 16);

            if (pass < 2) {
                *(u32*)(p + 2*l) = outpk;    // q: back in place
            } else {
                // K -> packed swizzled image: chunk ch=l>>2 at phys ch^(rr&15)
                const int ch = l >> 2;
                u16* dst = Kp + ((size_t)(kvh*32 + tile)*64 + rr)*128
                              + (ch ^ (rr & 15))*8 + (l & 3)*2;
                *(u32*)dst = outpk;
            }
        }
    }

    // ---- V transpose + swizzled pack ----
    __shared__ u16 tl[64][136];
    {
        const int t  = tid >> 2;
        const int c0 = (tid & 3) * 32;
        const u16* src = qkv + (size_t)(t0 + t)*QKV_N + NH*HD + NKV*HD + kvh*HD + c0;
        #pragma unroll
        for (int p2 = 0; p2 < 4; ++p2)
            *(u16x8*)(&tl[t][c0 + p2*8]) = *(const u16x8*)(src + p2*8);
    }
    __syncthreads();
    {
        u16* dstb = Vtp + (size_t)(kvh*32 + tile) * 128 * 64;
        #pragma unroll
        for (int i = 0; i < 4; ++i) {
            const int id = tid*4 + i;      // over (d,o): 128*8 chunks
            const int d = id >> 3;
            const int o = id & 7;
            const int sb = (o ^ (d & 7)) * 8;
            u16x8 v;
            #pragma unroll
            for (int j = 0; j < 8; ++j) v[j] = tl[sb + j][d];
            *(u16x8*)(dstb + d*64 + o*8) = v;
        }
    }
}

// ---------------------------------------------------------------------------
// Head-pair-merged split-s MFMA flash attention, DOUBLE-BUFFERED DMA.
// grid = 512 blocks x 512 thr (8 waves), 2 blocks/CU.
// ---------------------------------------------------------------------------
__global__ __launch_bounds__(512) void attn_mfma(
    const u16* __restrict__ qkv, const u16* __restrict__ Kp,
    const u16* __restrict__ Vtp,
    u16* __restrict__ Opart, float2* __restrict__ ml)
{
    const int id   = blockIdx.x;
    const int half = id >> 8;
    const int kvh  = id & 7;
    const int bid  = (id & 255) >> 3;              // 0..31
    const int qt   = half ? bid : 31 - bid;
    const int t0   = qt * 64;
    const int tid  = threadIdx.x;
    const int w    = tid >> 6;      // 0..7
    const int l    = tid & 63;
    const int q4   = l >> 4;        // quad group 0..3
    const int c    = l & 15;        // col (query) index within 16
    const int h    = kvh*2 + (w >> 2);
    const int wq   = w & 3;         // query group within head

    __shared__ short Ks[2][64 * 128];   // 2 x 16 KB
    __shared__ short Vts[2][128 * 64];  // 2 x 16 KB -> 64 KB total

    // ---- Q fragments in registers ----
    short8 bq[4];
    {
        const u16* qrow = qkv + (size_t)(t0 + wq*16 + c) * QKV_N + h*HD;
        #pragma unroll
        for (int kk = 0; kk < 4; ++kk)
            bq[kk] = *(const short8*)(qrow + kk*32 + q4*8);
    }

    float m_run = -3.0e38f, l_run = 0.f;
    floatx4 accO[8];
    #pragma unroll
    for (int db = 0; db < 8; ++db) accO[db] = (floatx4){0.f, 0.f, 0.f, 0.f};

    const float Cs = 0.12751744f;   // (1/sqrt(128)) * log2(e)

    const int nt  = qt + 1;
    const int nh0 = (nt + 1) >> 1;          // half0: [0,nh0), half1: [nh0,nt)
    const int tlo = half ? nh0 : 0;
    const int thi = half ? nt  : nh0;

    auto issue = [&](int tile, int buf) {
        const size_t tb = (size_t)(kvh*32 + tile) * 8192;
        const u16* g = (w < 4 ? Kp + tb + w*2048 : Vtp + tb + (w-4)*2048) + l*8;
        short* p = (w < 4) ? (Ks[buf] + w*2048) : (Vts[buf] + (w-4)*2048);
        #pragma unroll
        for (int i = 0; i < 4; ++i)
            __builtin_amdgcn_global_load_lds(
                (const __attribute__((address_space(1))) u32*)(g + i*512),
                (__attribute__((address_space(3))) u32*)(p + i*512), 16, 0, 0);
    };

    if (tlo < thi) issue(tlo, 0);
    int cur = 0;

    for (int tile = tlo; tile < thi; ++tile) {
        __syncthreads();   // drains buf[cur] DMA; orders vs prev compute
        if (tile + 1 < thi) issue(tile + 1, cur ^ 1);

        const short* Kc = Ks[cur];
        const short* Vc = Vts[cur];

        // ---- S^T = K Q^T ----
        floatx4 accS[4];
        #pragma unroll
        for (int sb = 0; sb < 4; ++sb) accS[sb] = (floatx4){0.f, 0.f, 0.f, 0.f};
        #pragma unroll
        for (int kk = 0; kk < 4; ++kk) {
            #pragma unroll
            for (int sb = 0; sb < 4; ++sb) {
                short8 ak = *(const short8*)(Kc + (sb*16 + c)*128 + ((kk*4 + q4) ^ c)*8);
                accS[sb] = __builtin_amdgcn_mfma_f32_16x16x32_bf16(ak, bq[kk], accS[sb], 0, 0, 0);
            }
        }

        // ---- causal mask on the diagonal tile ----
        if (tile == qt) {
            #pragma unroll
            for (int sb = 0; sb < 4; ++sb)
                #pragma unroll
                for (int r = 0; r < 4; ++r) {
                    const int s_loc = sb*16 + q4*4 + r;
                    const int t_loc = wq*16 + c;
                    if (s_loc > t_loc) accS[sb][r] = -1.0e30f;
                }
        }

        // ---- online softmax (per query col c) ----
        float mt = -3.0e38f;
        #pragma unroll
        for (int sb = 0; sb < 4; ++sb)
            #pragma unroll
            for (int r = 0; r < 4; ++r) mt = fmaxf(mt, accS[sb][r]);
        mt = fmaxf(mt, __shfl_xor(mt, 16));
        mt = fmaxf(mt, __shfl_xor(mt, 32));

        const float m_new = fmaxf(m_run, mt);
        const float alpha = exp2f((m_run - m_new) * Cs);  // 0 on first tile
        m_run = m_new;

        float P[4][4];
        float lsum = 0.f;
        #pragma unroll
        for (int sb = 0; sb < 4; ++sb)
            #pragma unroll
            for (int r = 0; r < 4; ++r) {
                const float e = exp2f((accS[sb][r] - m_new) * Cs);
                P[sb][r] = e;
                lsum += e;
            }
        lsum += __shfl_xor(lsum, 16);
        lsum += __shfl_xor(lsum, 32);
        l_run = l_run * alpha + lsum;

        // ---- rescale O by alpha (alpha per col c; O rows are 4q+r) ----
        #pragma unroll
        for (int r = 0; r < 4; ++r) {
            const float ar = __shfl(alpha, (l & 48) | (q4*4 + r));
            #pragma unroll
            for (int db = 0; db < 8; ++db) accO[db][r] *= ar;
        }

        // ---- pack P to bf16 pairs ----
        u32 Pp[4][2];
        #pragma unroll
        for (int sb = 0; sb < 4; ++sb)
            #pragma unroll
            for (int p = 0; p < 2; ++p)
                Pp[sb][p] = (u32)f2bf(P[sb][2*p]) | ((u32)f2bf(P[sb][2*p+1]) << 16);

        // ---- PV: O[m][d] += P[m][s] * Vt[d][s] ----
        const int src0 = ((2*q4    ) & 3) * 16 + c;
        const int src1 = ((2*q4 + 1) & 3) * 16 + c;
        const bool hiq = q4 >= 2;
        #pragma unroll
        for (int k2 = 0; k2 < 2; ++k2) {
            u32 x0 = __shfl(Pp[2*k2][0],   src0), y0 = __shfl(Pp[2*k2+1][0], src0);
            u32 x1 = __shfl(Pp[2*k2][1],   src0), y1 = __shfl(Pp[2*k2+1][1], src0);
            u32 x2 = __shfl(Pp[2*k2][0],   src1), y2 = __shfl(Pp[2*k2+1][0], src1);
            u32 x3 = __shfl(Pp[2*k2][1],   src1), y3 = __shfl(Pp[2*k2+1][1], src1);
            u32x4 av;
            av.x = hiq ? y0 : x0;  av.y = hiq ? y1 : x1;
            av.z = hiq ? y2 : x2;  av.w = hiq ? y3 : x3;
            const short8 aP = __builtin_bit_cast(short8, av);
            #pragma unroll
            for (int db = 0; db < 8; ++db) {
                short8 bv = *(const short8*)(Vc + (db*16 + c)*64 + (((k2*4 + q4) ^ (c & 7)))*8);
                accO[db] = __builtin_amdgcn_mfma_f32_16x16x32_bf16(aP, bv, accO[db], 0, 0, 0);
            }
        }
        cur ^= 1;
    }

    // ---- write UNNORMALIZED partial + (m,l) per query row ----
    const size_t pbase = (size_t)(half * NH + h) * T_TOK;
    #pragma unroll
    for (int r = 0; r < 4; ++r) {
        const int qloc = q4*4 + r;
        const float mr = __shfl(m_run, (l & 48) | qloc);
        const float lr = __shfl(l_run, (l & 48) | qloc);
        const int row_g = t0 + wq*16 + qloc;
        u16* op = Opart + (pbase + row_g) * HD;
        #pragma unroll
        for (int db = 0; db < 8; ++db)
            op[db*16 + c] = f2bf(accO[db][r]);
        if (c == 0) ml[pbase + row_g] = make_float2(mr, lr);
    }
}

// ---------------------------------------------------------------------------
// Merge the two split-s partials -> q slot of qkv (bf16). 8 elems/thread.
// ---------------------------------------------------------------------------
__global__ __launch_bounds__(256) void attn_combine(
    const u16* __restrict__ Opart, const float2* __restrict__ ml,
    u16* __restrict__ qkv)
{
    const int idx = blockIdx.x * 256 + threadIdx.x;
    const int c16 = idx & 15;                 // 16 chunks of 8 per row
    const int t   = (idx >> 4) & (T_TOK - 1);
    const int h   = idx >> 15;
    const size_t iA = (size_t)h * T_TOK + t;
    const size_t iB = (size_t)(NH + h) * T_TOK + t;
    const float2 a = ml[iA];
    const float2 b = ml[iB];
    const float Cs = 0.12751744f;
    const float mM = fmaxf(a.x, b.x);
    const float wA = exp2f((a.x - mM) * Cs);
    const float wB = exp2f((b.x - mM) * Cs);
    const float inv = 1.0f / (wA * a.y + wB * b.y);
    const u16x8 A = *(const u16x8*)(Opart + iA * HD + c16*8);
    const u16x8 B = *(const u16x8*)(Opart + iB * HD + c16*8);
    u16x8 o;
    #pragma unroll
    for (int j = 0; j < 8; ++j)
        o[j] = f2bf((wA * bf2f(A[j]) + wB * bf2f(B[j])) * inv);
    *(u16x8*)(qkv + (size_t)t * QKV_N + h * HD + c16*8) = o;
}

// ---------------------------------------------------------------------------
extern "C" void kernel_launch(void* const* d_in, const int* in_sizes, int n_in,
                              void* d_out, int out_size, void* d_ws, size_t ws_size,
                              hipStream_t stream)
{
    const float* hidden    = (const float*)d_in[0];   // T x HID
    const int*   positions = (const int*)  d_in[1];   // T
    const float* qkv_w     = (const float*)d_in[2];   // 4096 x 2048
    const float* o_w       = (const float*)d_in[3];   // 2048 x 2048
    const float* q_norm_w  = (const float*)d_in[4];   // 128
    const float* k_norm_w  = (const float*)d_in[5];   // 128
    float* out = (float*)d_out;                       // T x HID (f32)

    // ws: [qkvbf 16MB][wbf 16MB][abf 8MB][Kp 4MB][Vtp 4MB] = 48 MB
    u16* qkvbf = (u16*)d_ws;
    u16* wbf   = qkvbf + (size_t)T_TOK * QKV_N;
    u16* abf   = wbf   + (size_t)QKV_N * HID;
    u16* kpb   = abf   + (size_t)T_TOK * HID;
    u16* vpb   = kpb   + (size_t)NKV * T_TOK * HD;

    static bool s_attr = false;
    if (!s_attr) {
        (void)hipFuncSetAttribute(
            reinterpret_cast<const void*>(&gemm_bt_8p<true>),
            hipFuncAttributeMaxDynamicSharedMemorySize, 147456);
        (void)hipFuncSetAttribute(
            reinterpret_cast<const void*>(&gemm_bt_8p<false>),
            hipFuncAttributeMaxDynamicSharedMemorySize, 147456);
        s_attr = true;
    }

    cvt_f32_bf16<<<(T_TOK*HID)/2048, 256, 0, stream>>>(hidden, abf);
    cvt_f32_bf16<<<(QKV_N*HID)/2048, 256, 0, stream>>>(qkv_w, wbf);

    // 1) qkv(bf16) = hidden @ qkv_w^T   (M=2048, N=4096, K=2048; 256 blocks)
    gemm_bt_8p<true><<<dim3(QKV_N/GBN, T_TOK/GBM), 512, 147456, stream>>>(
        abf, wbf, qkvbf, HID, HID, HID, QKV_N);

    // 2) fused rmsnorm+rope (q in place, K packed) + V transpose-pack
    prep<<<dim3(T_TOK/64, NKV), 256, 0, stream>>>(
        qkvbf, positions, q_norm_w, k_norm_w, kpb, vpb);

    // 3) head-pair-merged split-s MFMA flash attention (double-buffered DMA)
    attn_mfma<<<512, 512, 0, stream>>>(qkvbf, kpb, vpb, wbf, (float2*)abf);

    // 3b) combine partials -> q slots of qkv
    attn_combine<<<(NH*T_TOK*16)/256, 256, 0, stream>>>(
        wbf, (const float2*)abf, qkvbf);

    // 4) out(f32) = o @ o_w^T  (M=2048, N=2048, K=2048; 128 blocks)
    cvt_f32_bf16<<<(HID*HID)/2048, 256, 0, stream>>>(o_w, abf);
    gemm_bt_8p<false><<<dim3(HID/GBN, T_TOK/GBM), 512, 147456, stream>>>(
        qkvbf, abf, out, HID, QKV_N, HID, HID);
}

// Round 2
// 240.005 us; speedup vs baseline: 1.1912x; 1.0371x over previous
//
#include <hip/hip_runtime.h>
#include <math.h>

// Qwen3Attention: T=2048, HID=2048, H=16, KV=8, D=128
#define T_TOK 2048
#define HID 2048
#define NH 16
#define NKV 8
#define HD 128
#define QKV_N 4096
#define EPS 1e-6f

typedef unsigned short u16;
typedef unsigned int   u32;
typedef __attribute__((ext_vector_type(8))) u16   u16x8;
typedef __attribute__((ext_vector_type(8))) short short8;
typedef __attribute__((ext_vector_type(4))) float floatx4;
typedef __attribute__((ext_vector_type(16))) float f32x16;
typedef __attribute__((ext_vector_type(4))) u32   u32x4;

__device__ __forceinline__ u16 f2bf(float x) {           // RNE f32->bf16
    u32 u = __float_as_uint(x);
    u = (u + 0x7fffu + ((u >> 16) & 1u)) >> 16;
    return (u16)u;
}
__device__ __forceinline__ float bf2f(u16 h) {
    return __uint_as_float(((u32)h) << 16);
}
__device__ __forceinline__ u32 cvtpk_bf16(float lo, float hi) {
    u32 r;
    asm("v_cvt_pk_bf16_f32 %0, %1, %2" : "=v"(r) : "v"(lo), "v"(hi));
    return r;
}

// ---------------------------------------------------------------------------
// f32 -> bf16, 8 elems/thread helper.
// ---------------------------------------------------------------------------
__device__ __forceinline__ void cvt8(const float* __restrict__ in,
                                     u16* __restrict__ out, size_t i)
{
    float4 a = *(const float4*)(in + i);
    float4 b = *(const float4*)(in + i + 4);
    u16x8 o;
    o[0] = f2bf(a.x); o[1] = f2bf(a.y); o[2] = f2bf(a.z); o[3] = f2bf(a.w);
    o[4] = f2bf(b.x); o[5] = f2bf(b.y); o[6] = f2bf(b.z); o[7] = f2bf(b.w);
    *(u16x8*)(out + i) = o;
}

// hidden (2048 blk) + qkv_w (4096 blk) in one launch.
__global__ __launch_bounds__(256) void cvt_pair(
    const float* __restrict__ ina, u16* __restrict__ outa,
    const float* __restrict__ inb, u16* __restrict__ outb)
{
    const int bid = blockIdx.x;
    if (bid < 2048) cvt8(ina, outa, ((size_t)bid * 256 + threadIdx.x) * 8);
    else            cvt8(inb, outb, ((size_t)(bid - 2048) * 256 + threadIdx.x) * 8);
}

// ---------------------------------------------------------------------------
// bf16 MFMA GEMM, T2+T3+T4+T5 stack: C[M,N] = A[M,K]*B[N,K]^T  (unchanged)
// ---------------------------------------------------------------------------
#define GBM 256
#define GBN 128
#define GBK 64
#define BUFSH 24576

#define WAITV6 asm volatile("s_waitcnt vmcnt(6)" ::: "memory")
#define WAITV0 asm volatile("s_waitcnt vmcnt(0)" ::: "memory")
#define LGKM0  asm volatile("s_waitcnt lgkmcnt(0)" ::: "memory")
#define BARR   asm volatile("s_barrier" ::: "memory")
#define SB     __builtin_amdgcn_sched_barrier(0)

#define STAGEU(i, tt, dstb) \
    __builtin_amdgcn_global_load_lds( \
        (const __attribute__((address_space(1))) u32*)(gsrc[i] + (size_t)(tt)*GBK), \
        (__attribute__((address_space(3))) u32*)((dstb) + loff[i]), 16, 0, 0)

#define RD_A(dst, srcb, f) do { \
    dst[0] = *(const short8*)((srcb) + arow + (f)*1024 + achunk0); \
    dst[1] = *(const short8*)((srcb) + arow + (f)*1024 + achunk1); } while (0)

#define RD_B(dst, srcb) do { \
    _Pragma("unroll") \
    for (int j_ = 0; j_ < 4; ++j_) { \
        dst[j_][0] = *(const short8*)((srcb) + 16384 + brow + j_*1024 + achunk0); \
        dst[j_][1] = *(const short8*)((srcb) + 16384 + brow + j_*1024 + achunk1); } } while (0)

#define MM(f, aa, bb) do { \
    __builtin_amdgcn_s_setprio(1); \
    _Pragma("unroll") \
    for (int j_ = 0; j_ < 4; ++j_) { \
        acc[f][j_] = __builtin_amdgcn_mfma_f32_16x16x32_bf16(aa[0], bb[j_][0], acc[f][j_], 0, 0, 0); \
        acc[f][j_] = __builtin_amdgcn_mfma_f32_16x16x32_bf16(aa[1], bb[j_][1], acc[f][j_], 0, 0, 0); } \
    __builtin_amdgcn_s_setprio(0); } while (0)

#define TILE(t, CURB, NXTB, THDB, BBC, BBN) do { \
    const bool st_ = (t) + 2 < nt; \
    if (st_) { STAGEU(0, (t)+2, THDB); STAGEU(1, (t)+2, THDB); } \
    RD_A(aP1, CURB, 1); SB; \
    MM(0, aP0, BBC); SB; \
    if (st_) { STAGEU(2, (t)+2, THDB); STAGEU(3, (t)+2, THDB); } \
    RD_A(aP0, CURB, 2); SB; \
    MM(1, aP1, BBC); SB; \
    if (st_) { STAGEU(4, (t)+2, THDB); STAGEU(5, (t)+2, THDB); } \
    RD_A(aP1, CURB, 3); SB; \
    MM(2, aP0, BBC); \
    if ((t) + 1 < nt) { \
        if (st_) { WAITV6; } else { WAITV0; } \
        LGKM0; BARR; SB; \
        RD_B(BBN, NXTB); RD_A(aP0, NXTB, 0); \
    } \
    SB; \
    MM(3, aP1, BBC); SB; \
} while (0)

template<bool OUT_BF16>
__global__ __launch_bounds__(512, 2) void gemm_bt_8p(
    const u16* __restrict__ A, const u16* __restrict__ B,
    void* __restrict__ Cv, int K, int lda, int ldb, int ldc)
{
    extern __shared__ short lds[];
    const int tid = threadIdx.x;
    const int w  = tid >> 6;
    const int l  = tid & 63;
    const int m0 = blockIdx.y * GBM;
    const int n0 = blockIdx.x * GBN;
    const int mr = (w >> 1) * 64;
    const int nc = (w & 1) * 64;
    const int cc = l & 15;
    const int q4 = l >> 4;

    const int lr = l >> 3;
    const int gchunk = ((l & 7) ^ (lr & 7)) * 8;
    const u16* gsrc[6]; int loff[6];
    #pragma unroll
    for (int i = 0; i < 6; ++i) {
        const int u = w * 6 + i;
        if (u < 32) {
            gsrc[i] = A + (size_t)(m0 + u*8 + lr) * lda + gchunk;
            loff[i] = u * 512;
        } else {
            const int v = u - 32;
            gsrc[i] = B + (size_t)(n0 + v*8 + lr) * ldb + gchunk;
            loff[i] = 16384 + v * 512;
        }
    }

    const int achunk0 = ((q4)     ^ (cc & 7)) * 8;
    const int achunk1 = ((4 + q4) ^ (cc & 7)) * 8;
    const int arow = (mr + cc) * 64;
    const int brow = (nc + cc) * 64;

    floatx4 acc[4][4];
    #pragma unroll
    for (int f = 0; f < 4; ++f)
        #pragma unroll
        for (int j = 0; j < 4; ++j) acc[f][j] = (floatx4){0.f, 0.f, 0.f, 0.f};

    short8 aP0[2], aP1[2], bbE[4][2], bbO[4][2];
    short* b0 = lds;
    short* b1 = lds + BUFSH;
    short* b2 = lds + 2 * BUFSH;
    const int nt = K >> 6;

    #pragma unroll
    for (int i = 0; i < 6; ++i) STAGEU(i, 0, b0);
    #pragma unroll
    for (int i = 0; i < 6; ++i) STAGEU(i, 1, b1);
    WAITV6; BARR; SB;
    RD_B(bbE, b0); RD_A(aP0, b0, 0);

    short *CURB = b0, *NXTB = b1, *THDB = b2;
    for (int t = 0; t < nt; t += 2) {
        TILE(t, CURB, NXTB, THDB, bbE, bbO);
        { short* tmp = CURB; CURB = NXTB; NXTB = THDB; THDB = tmp; }
        TILE(t + 1, CURB, NXTB, THDB, bbO, bbE);
        { short* tmp = CURB; CURB = NXTB; NXTB = THDB; THDB = tmp; }
    }

    const int r0 = q4 * 4;
    #pragma unroll
    for (int f = 0; f < 4; ++f)
        #pragma unroll
        for (int j = 0; j < 4; ++j)
            #pragma unroll
            for (int r = 0; r < 4; ++r) {
                const int row = m0 + mr + f*16 + r0 + r;
                const int col = n0 + nc + j*16 + cc;
                if (OUT_BF16)
                    ((u16*)Cv)[(size_t)row * ldc + col] = f2bf(acc[f][j][r]);
                else
                    ((float*)Cv)[(size_t)row * ldc + col] = acc[f][j][r];
            }
}

// ---------------------------------------------------------------------------
// Fused prep (RMSNorm+RoPE q/K, K packed swizzled, V transpose-pack) merged
// with o_w f32->bf16 cvt. blocks [0,256) = prep, [256, 2304) = cvt chunks.
// ---------------------------------------------------------------------------
__global__ __launch_bounds__(256) void prep_cvt(
    u16* __restrict__ qkv, const int* __restrict__ positions,
    const float* __restrict__ qw, const float* __restrict__ kw,
    u16* __restrict__ Kp, u16* __restrict__ Vtp,
    const float* __restrict__ ow, u16* __restrict__ owbf)
{
    const int bid = blockIdx.x;
    if (bid >= 256) {
        cvt8(ow, owbf, ((size_t)(bid - 256) * 256 + threadIdx.x) * 8);
        return;
    }
    const int tile = bid & 31, kvh = bid >> 5;
    const int tid = threadIdx.x;
    const int w = tid >> 6, l = tid & 63;
    const int t0 = tile * 64;

    const float qw0 = qw[2*l], qw1 = qw[2*l+1];
    const float kw0 = kw[2*l], kw1 = kw[2*l+1];
    const int   i0  = (2*l) & 63;
    const float if0 = exp2f(-(float)i0     * 0.311430758895690f); // log2(1e6)/64
    const float if1 = exp2f(-(float)(i0+1) * 0.311430758895690f);

    for (int rr = w; rr < 64; rr += 4) {
        const int t = t0 + rr;
        const int pos = positions[t];
        const float a0 = (float)pos * if0;
        const float a1 = (float)pos * if1;
        const float s0 = sinf(a0), c0 = cosf(a0);
        const float s1 = sinf(a1), c1 = cosf(a1);

        #pragma unroll
        for (int pass = 0; pass < 3; ++pass) {
            const int off = (pass < 2) ? (2*kvh + pass)*HD : NH*HD + kvh*HD;
            const float w0 = (pass < 2) ? qw0 : kw0;
            const float w1 = (pass < 2) ? qw1 : kw1;
            u16* p = qkv + (size_t)t*QKV_N + off;

            const u32 pk = *(const u32*)(p + 2*l);
            const float x0 = bf2f((u16)pk), x1 = bf2f((u16)(pk >> 16));
            float ss = x0*x0 + x1*x1;
            #pragma unroll
            for (int x = 1; x < 64; x <<= 1) ss += __shfl_xor(ss, x);
            const float rs = rsqrtf(ss * (1.0f/128.0f) + EPS);
            const float xn0 = x0 * rs * w0, xn1 = x1 * rs * w1;
            const float px0 = __shfl_xor(xn0, 32);
            const float px1 = __shfl_xor(xn1, 32);

            float o0, o1;
            if (l < 32) { o0 = xn0*c0 - px0*s0; o1 = xn1*c1 - px1*s1; }
            else        { o0 = xn0*c0 + px0*s0; o1 = xn1*c1 + px1*s1; }
            const u32 outpk = (u32)f2bf(o0) | ((u32)f2bf(o1) << 16);

            if (pass < 2) {
                *(u32*)(p + 2*l) = outpk;
            } else {
                const int ch = l >> 2;
                u16* dst = Kp + ((size_t)(kvh*32 + tile)*64 + rr)*128
                              + (ch ^ (rr & 15))*8 + (l & 3)*2;
                *(u32*)dst = outpk;
            }
        }
    }

    // ---- V transpose + swizzled pack ----
    __shared__ u16 tl[64][136];
    {
        const int t  = tid >> 2;
        const int c0 = (tid & 3) * 32;
        const u16* src = qkv + (size_t)(t0 + t)*QKV_N + NH*HD + NKV*HD + kvh*HD + c0;
        #pragma unroll
        for (int p2 = 0; p2 < 4; ++p2)
            *(u16x8*)(&tl[t][c0 + p2*8]) = *(const u16x8*)(src + p2*8);
    }
    __syncthreads();
    {
        u16* dstb = Vtp + (size_t)(kvh*32 + tile) * 128 * 64;
        #pragma unroll
        for (int i = 0; i < 4; ++i) {
            const int id = tid*4 + i;
            const int d = id >> 3;
            const int o = id & 7;
            const int sb = (o ^ (d & 7)) * 8;
            u16x8 v;
            #pragma unroll
            for (int j = 0; j < 8; ++j) v[j] = tl[sb + j][d];
            *(u16x8*)(dstb + d*64 + o*8) = v;
        }
    }
}

// ---------------------------------------------------------------------------
// 32x32-MFMA flash attention: 256 thr = 4 waves, 1 head, q-tile=128 (32 q/wave),
// kv-tile=64, split-2 causal halves, double-buffered global_load_lds.
// Halved LDS-read per FLOP vs 16x16 version; T12 cvt_pk+permlane32_swap for
// P redistribution; T13 defer-max; T5 setprio.
// grid = 512: kvh = id&7 (XCD-local K/V); u=id>>3: half=u>>5, hp=(u&31)&1,
// bq=(u&31)>>1; qt = half ? bq : 15-bq  (long+short pairing per CU).
// ---------------------------------------------------------------------------
__global__ __launch_bounds__(256, 2) void attn_mfma32(
    const u16* __restrict__ qkv, const u16* __restrict__ Kp,
    const u16* __restrict__ Vtp,
    u16* __restrict__ Opart, float2* __restrict__ ml)
{
    const int id   = blockIdx.x;
    const int kvh  = id & 7;
    const int u    = id >> 3;
    const int half = u >> 5;
    const int v    = u & 31;
    const int hp   = v & 1;
    const int bq   = v >> 1;
    const int qt   = half ? bq : 15 - bq;
    const int h    = kvh*2 + hp;
    const int t0q  = qt * 128;

    const int tid = threadIdx.x;
    const int w   = tid >> 6;       // wave = q-group (32 rows each)
    const int l   = tid & 63;
    const int q31 = l & 31;
    const int hi  = l >> 5;

    __shared__ short Ks[2][8192];   // 2 x 16 KB (64 kv x 128 d, chunk-swizzled)
    __shared__ short Vts[2][8192];  // 2 x 16 KB (128 d x 64 s, chunk-swizzled)

    // ---- Q B-frags in registers: B[n=q31][k = ks*16 + hi*8 + 0..7] ----
    short8 qf[8];
    {
        const u16* qrow = qkv + (size_t)(t0q + w*32 + q31) * QKV_N + h*HD;
        #pragma unroll
        for (int ks = 0; ks < 8; ++ks)
            qf[ks] = *(const short8*)(qrow + ks*16 + hi*8);
    }

    float m_run = -3.0e38f, l_run = 0.f;
    f32x16 accO[4];                 // O[q rows via reg][d = nd*32 + q31]
    #pragma unroll
    for (int nd = 0; nd < 4; ++nd)
        #pragma unroll
        for (int r = 0; r < 16; ++r) accO[nd][r] = 0.f;

    const float Cs = 0.12751744f;   // (1/sqrt(128)) * log2(e)

    const int nt  = 2*qt + 2;
    const int nh0 = qt + 1;
    const int tlo = half ? nh0 : 0;
    const int thi = half ? nt  : nh0;

    auto issue = [&](int tile, int buf) {
        const size_t tb = (size_t)(kvh*32 + tile) * 8192;
        const u16* g = ((w < 2) ? Kp : Vtp) + tb + (w & 1)*4096 + l*8;
        short* p = ((w < 2) ? Ks[buf] : Vts[buf]) + (w & 1)*4096 + l*8;
        #pragma unroll
        for (int i = 0; i < 8; ++i)
            __builtin_amdgcn_global_load_lds(
                (const __attribute__((address_space(1))) u32*)(g + i*512),
                (__attribute__((address_space(3))) u32*)(p + i*512), 16, 0, 0);
    };

    issue(tlo, 0);
    int cur = 0;

    for (int tile = tlo; tile < thi; ++tile) {
        __syncthreads();            // drains buf[cur] DMA
        if (tile + 1 < thi) issue(tile + 1, cur ^ 1);

        const short* Kc = Ks[cur];
        const short* Vc = Vts[cur];

        // ---- S^T = K Q^T : accS[mt], rows kv = mt*32 + (r&3)+8*(r>>2)+4*hi,
        //      cols q = q31 ----
        f32x16 accS0, accS1;
        #pragma unroll
        for (int r = 0; r < 16; ++r) { accS0[r] = 0.f; accS1[r] = 0.f; }

        __builtin_amdgcn_s_setprio(1);
        #pragma unroll
        for (int ks = 0; ks < 8; ++ks) {
            const int pc = ((2*ks + hi) ^ (q31 & 15)) * 8;
            short8 a0 = *(const short8*)(Kc + q31*128 + pc);
            short8 a1 = *(const short8*)(Kc + (32 + q31)*128 + pc);
            accS0 = __builtin_amdgcn_mfma_f32_32x32x16_bf16(a0, qf[ks], accS0, 0, 0, 0);
            accS1 = __builtin_amdgcn_mfma_f32_32x32x16_bf16(a1, qf[ks], accS1, 0, 0, 0);
        }
        __builtin_amdgcn_s_setprio(0);

        // ---- causal mask ----
        if (tile >= 2*qt) {
            const int qg = w*32 + q31 + t0q - tile*64;
            #pragma unroll
            for (int r = 0; r < 16; ++r) {
                const int kvb = (r&3) + 8*(r>>2) + (hi<<2);
                if (kvb > qg)      accS0[r] = -1.0e30f;
                if (kvb + 32 > qg) accS1[r] = -1.0e30f;
            }
        }

        // ---- online softmax (per q col = lane pair l, l^32) ----
        float mx = accS0[0];
        #pragma unroll
        for (int r = 1; r < 16; ++r) mx = fmaxf(mx, accS0[r]);
        #pragma unroll
        for (int r = 0; r < 16; ++r) mx = fmaxf(mx, accS1[r]);
        mx = fmaxf(mx, __shfl_xor(mx, 32));

        // T13 defer-max: only rescale when max grew by >11.76 (=1.5/Cs)
        if (__any(mx > m_run + 11.76f)) {
            const float m_new = fmaxf(m_run, mx);
            const float alpha = exp2f((m_run - m_new) * Cs);
            l_run *= alpha;
            m_run = m_new;
            #pragma unroll
            for (int r = 0; r < 16; ++r) {
                const float ar = __shfl(alpha, ((r&3) + 8*(r>>2)) + (hi<<2));
                accO[0][r] *= ar; accO[1][r] *= ar;
                accO[2][r] *= ar; accO[3][r] *= ar;
            }
        }

        const float mb = m_run * Cs;
        float lsum = 0.f;
        #pragma unroll
        for (int r = 0; r < 16; ++r) {
            const float e0 = exp2f(accS0[r]*Cs - mb);
            const float e1 = exp2f(accS1[r]*Cs - mb);
            accS0[r] = e0; accS1[r] = e1;
            lsum += e0 + e1;
        }
        lsum += __shfl_xor(lsum, 32);
        l_run += lsum;

        // ---- PV: O[q][d] += P[q][s] Vt[d][s]; A-frag via cvt_pk+permlane ----
        __builtin_amdgcn_s_setprio(1);
        #pragma unroll
        for (int ks = 0; ks < 4; ++ks) {
            const int R = (ks & 1) * 8;
            u32 x0, x1, x2, x3;
            if (ks < 2) {
                x0 = cvtpk_bf16(accS0[R+0], accS0[R+1]);
                x1 = cvtpk_bf16(accS0[R+2], accS0[R+3]);
                x2 = cvtpk_bf16(accS0[R+4], accS0[R+5]);
                x3 = cvtpk_bf16(accS0[R+6], accS0[R+7]);
            } else {
                x0 = cvtpk_bf16(accS1[R+0], accS1[R+1]);
                x1 = cvtpk_bf16(accS1[R+2], accS1[R+3]);
                x2 = cvtpk_bf16(accS1[R+4], accS1[R+5]);
                x3 = cvtpk_bf16(accS1[R+6], accS1[R+7]);
            }
            // x0.high_lanes <-> x2.low_lanes ; x1.high <-> x3.low
            asm("v_permlane32_swap_b32 %0, %1" : "+v"(x0), "+v"(x2));
            asm("v_permlane32_swap_b32 %0, %1" : "+v"(x1), "+v"(x3));
            u32x4 aw; aw.x = x0; aw.y = x1; aw.z = x2; aw.w = x3;
            const short8 aP = __builtin_bit_cast(short8, aw);
            #pragma unroll
            for (int nd = 0; nd < 4; ++nd) {
                short8 bv = *(const short8*)(Vc + (nd*32 + q31)*64
                                             + ((2*ks + hi) ^ (q31 & 7))*8);
                accO[nd] = __builtin_amdgcn_mfma_f32_32x32x16_bf16(aP, bv, accO[nd], 0, 0, 0);
            }
        }
        __builtin_amdgcn_s_setprio(0);

        cur ^= 1;
    }

    // ---- write UNNORMALIZED partial + (m,l) per q row ----
    const size_t pbase = (size_t)(half * NH + h) * T_TOK;
    #pragma unroll
    for (int r = 0; r < 16; ++r) {
        const int qr = (r&3) + 8*(r>>2) + (hi<<2);
        u16* op = Opart + (pbase + t0q + w*32 + qr) * HD;
        op[q31]      = f2bf(accO[0][r]);
        op[32 + q31] = f2bf(accO[1][r]);
        op[64 + q31] = f2bf(accO[2][r]);
        op[96 + q31] = f2bf(accO[3][r]);
    }
    if (l < 32)
        ml[pbase + t0q + w*32 + l] = make_float2(m_run, l_run);
}

// ---------------------------------------------------------------------------
// Merge the two split-s partials -> q slot of qkv (bf16). 8 elems/thread.
// ---------------------------------------------------------------------------
__global__ __launch_bounds__(256) void attn_combine(
    const u16* __restrict__ Opart, const float2* __restrict__ ml,
    u16* __restrict__ qkv)
{
    const int idx = blockIdx.x * 256 + threadIdx.x;
    const int c16 = idx & 15;
    const int t   = (idx >> 4) & (T_TOK - 1);
    const int h   = idx >> 15;
    const size_t iA = (size_t)h * T_TOK + t;
    const size_t iB = (size_t)(NH + h) * T_TOK + t;
    const float2 a = ml[iA];
    const float2 b = ml[iB];
    const float Cs = 0.12751744f;
    const float mM = fmaxf(a.x, b.x);
    const float wA = exp2f((a.x - mM) * Cs);
    const float wB = exp2f((b.x - mM) * Cs);
    const float inv = 1.0f / (wA * a.y + wB * b.y);
    const u16x8 A = *(const u16x8*)(Opart + iA * HD + c16*8);
    const u16x8 B = *(const u16x8*)(Opart + iB * HD + c16*8);
    u16x8 o;
    #pragma unroll
    for (int j = 0; j < 8; ++j)
        o[j] = f2bf((wA * bf2f(A[j]) + wB * bf2f(B[j])) * inv);
    *(u16x8*)(qkv + (size_t)t * QKV_N + h * HD + c16*8) = o;
}

// ---------------------------------------------------------------------------
extern "C" void kernel_launch(void* const* d_in, const int* in_sizes, int n_in,
                              void* d_out, int out_size, void* d_ws, size_t ws_size,
                              hipStream_t stream)
{
    const float* hidden    = (const float*)d_in[0];   // T x HID
    const int*   positions = (const int*)  d_in[1];   // T
    const float* qkv_w     = (const float*)d_in[2];   // 4096 x 2048
    const float* o_w       = (const float*)d_in[3];   // 2048 x 2048
    const float* q_norm_w  = (const float*)d_in[4];   // 128
    const float* k_norm_w  = (const float*)d_in[5];   // 128
    float* out = (float*)d_out;                       // T x HID (f32)

    // ws: [qkvbf 16MB][wbf 16MB][abf 8MB][Kp 4MB][Vtp 4MB] = 48 MB
    // wbf -> Opart during attn; abf: hidden bf16 -> o_w bf16 (after gemm1).
    // ml lives in d_out (dead until gemm2 overwrites it).
    u16* qkvbf = (u16*)d_ws;
    u16* wbf   = qkvbf + (size_t)T_TOK * QKV_N;
    u16* abf   = wbf   + (size_t)QKV_N * HID;
    u16* kpb   = abf   + (size_t)T_TOK * HID;
    u16* vpb   = kpb   + (size_t)NKV * T_TOK * HD;

    static bool s_attr = false;
    if (!s_attr) {
        (void)hipFuncSetAttribute(
            reinterpret_cast<const void*>(&gemm_bt_8p<true>),
            hipFuncAttributeMaxDynamicSharedMemorySize, 147456);
        (void)hipFuncSetAttribute(
            reinterpret_cast<const void*>(&gemm_bt_8p<false>),
            hipFuncAttributeMaxDynamicSharedMemorySize, 147456);
        s_attr = true;
    }

    // 0) hidden + qkv_w -> bf16 (one launch)
    cvt_pair<<<6144, 256, 0, stream>>>(hidden, abf, qkv_w, wbf);

    // 1) qkv(bf16) = hidden @ qkv_w^T
    gemm_bt_8p<true><<<dim3(QKV_N/GBN, T_TOK/GBM), 512, 147456, stream>>>(
        abf, wbf, qkvbf, HID, HID, HID, QKV_N);

    // 2) prep (rmsnorm+rope, K/V pack) + o_w -> bf16 into abf (dead after gemm1)
    prep_cvt<<<2304, 256, 0, stream>>>(
        qkvbf, positions, q_norm_w, k_norm_w, kpb, vpb, o_w, abf);

    // 3) 32x32-MFMA split-s flash attention; ml -> d_out scratch
    attn_mfma32<<<512, 256, 0, stream>>>(qkvbf, kpb, vpb, wbf, (float2*)out);

    // 3b) combine partials -> q slots of qkv
    attn_combine<<<(NH*T_TOK*16)/256, 256, 0, stream>>>(
        wbf, (const float2*)out, qkvbf);

    // 4) out(f32) = o @ o_w^T
    gemm_bt_8p<false><<<dim3(HID/GBN, T_TOK/GBM), 512, 147456, stream>>>(
        qkvbf, abf, out, HID, QKV_N, HID, HID);
}